// Round 7
// baseline (995.216 us; speedup 1.0000x reference)
//
#include <hip/hip_runtime.h>
#include <stdint.h>

#define NN 50000
#define EE 800000
#define IN_DIM 128
#define OUT_DIM 32
#define HEADS 8
#define FF 256
#define SH 128
#define NPAD 50048     // NN rounded up to 64
#define FEXT 272       // 256 feat cols + 8 el-proj + 8 er-proj
#define CAP 64         // per-dst bucket capacity (max degree ~45 << 64)
#define CSTRIDE 16     // one counter per 64B line (kills atomic line contention)

#define GEMM_BLKS 782  // NPAD/64
#define FILL_G   6250  // 2*EE/256 — merged fill (2x line parallelism = 128 µs floor)
#define PULL_G   12500 // NN/4

// prep blocks: WsemT (128) + BT_a (FEXT) + BT_b (FEXT)
#define P_BTA0   128
#define P_BTB0   (P_BTA0 + FEXT)
#define P_G      (P_BTB0 + FEXT)

// megaF: gemm blocks FIRST (seed CUs with MFMA work), merged fill floods after
#define F_GEMM   (2 * GEMM_BLKS)
#define F_G      (F_GEMM + FILL_G)

#define C_G      (2 * PULL_G)   // merged pulls + fused per-wave sem

#define QSLOTS   16    // qsum spread: 16 line-padded accumulators per metapath

typedef short s16x8 __attribute__((ext_vector_type(8)));
typedef float f32x4 __attribute__((ext_vector_type(4)));
typedef float f32x2 __attribute__((ext_vector_type(2)));

__device__ __forceinline__ float b2f(unsigned short u) {
    union { unsigned int i; float f; } v; v.i = ((unsigned int)u) << 16; return v.f;
}
__device__ __forceinline__ unsigned short f2b(float f) {
    union { float f; unsigned int i; } v; v.f = f;
    unsigned int i = v.i;
    unsigned int r = (i + 0x7FFFu + ((i >> 16) & 1u)) >> 16;
    return (unsigned short)r;
}

__device__ __forceinline__ void buildBT_one(
    const float* __restrict__ W, const float* __restrict__ al,
    const float* __restrict__ ar, unsigned short* __restrict__ BT,
    int fp, int k)
{
    float v;
    if (fp < FF) {
        v = W[(size_t)k * FF + fp];
    } else if (fp < FF + 8) {
        int hh = fp - FF;
        float s = 0.f;
        #pragma unroll
        for (int d = 0; d < 32; ++d) s += W[(size_t)k * FF + hh * 32 + d] * al[hh * 32 + d];
        v = s;
    } else {
        int hh = fp - FF - 8;
        float s = 0.f;
        #pragma unroll
        for (int d = 0; d < 32; ++d) s += W[(size_t)k * FF + hh * 32 + d] * ar[hh * 32 + d];
        v = s;
    }
    BT[(size_t)fp * IN_DIM + k] = f2b(v);
}

// ---- fill: one edge per thread; rank from atomicAdd return ----
__device__ __forceinline__ void dev_fill(
    int idx, const int* __restrict__ src, const int* __restrict__ dst,
    int* __restrict__ counts, unsigned short* __restrict__ perm)
{
    int d = dst[idx];
    int r = atomicAdd(&counts[d * CSTRIDE], 1);
    if (r < CAP) perm[d * CAP + r] = (unsigned short)src[idx];
}

// ---- gemm: feat = h@W (bf16 MFMA), el/er fused as extra BT columns ----
__device__ __forceinline__ void dev_gemm(
    int gb, int t, const float* __restrict__ h,
    const unsigned short* __restrict__ BT,
    unsigned short* __restrict__ feat,
    float* __restrict__ el, float* __restrict__ er)
{
    int wave = t >> 6, lane = t & 63;
    int quad = lane >> 4, l16 = lane & 15;
    int nbase = gb * 64 + wave * 16;
    int n = nbase + l16;
    int nr = (n < NN) ? n : (NN - 1);   // clamp: pad rows must not read OOB
    const float* hrow = h + (size_t)nr * IN_DIM + quad * 8;
    s16x8 nfr[4];
    #pragma unroll
    for (int kt = 0; kt < 4; ++kt) {
        float4 p0 = *(const float4*)(hrow + kt * 32);
        float4 p1 = *(const float4*)(hrow + kt * 32 + 4);
        s16x8 v;
        v[0] = (short)f2b(p0.x); v[1] = (short)f2b(p0.y);
        v[2] = (short)f2b(p0.z); v[3] = (short)f2b(p0.w);
        v[4] = (short)f2b(p1.x); v[5] = (short)f2b(p1.y);
        v[6] = (short)f2b(p1.z); v[7] = (short)f2b(p1.w);
        nfr[kt] = v;
    }
    bool live = (n < NN);
    #pragma unroll 1
    for (int ft = 0; ft < 17; ++ft) {
        const unsigned short* brow = BT + (size_t)(ft * 16 + l16) * IN_DIM + quad * 8;
        f32x4 c = {0.f, 0.f, 0.f, 0.f};
        #pragma unroll
        for (int kt = 0; kt < 4; ++kt) {
            s16x8 ffr = *(const s16x8*)(brow + kt * 32);
            c = __builtin_amdgcn_mfma_f32_16x16x32_bf16(ffr, nfr[kt], c, 0, 0, 0);
        }
        if (ft < 16) {
            if (live) {
                ushort4 r;
                r.x = f2b(c[0]); r.y = f2b(c[1]); r.z = f2b(c[2]); r.w = f2b(c[3]);
                *(ushort4*)(feat + (size_t)n * FF + ft * 16 + quad * 4) = r;
            }
        } else if (live) {
            #pragma unroll
            for (int r = 0; r < 4; ++r) {
                int jp = quad * 4 + r;
                if (jp < 8) el[n * HEADS + jp] = c[r];
                else        er[n * HEADS + (jp - 8)] = c[r];
            }
        }
    }
}

// ---- prep: WsemT ∪ BT_a ∪ BT_b (tiny) ----
__global__ __launch_bounds__(256) void prep(
    const float* __restrict__ Wsem, unsigned short* __restrict__ WsemT,
    const float* __restrict__ W_a, const float* __restrict__ al_a,
    const float* __restrict__ ar_a, unsigned short* __restrict__ BT_a,
    const float* __restrict__ W_b, const float* __restrict__ al_b,
    const float* __restrict__ ar_b, unsigned short* __restrict__ BT_b)
{
    int b = blockIdx.x, t = threadIdx.x;
    if (b < P_BTA0) {
        WsemT[b * FF + t] = f2b(Wsem[(size_t)t * SH + b]);
    } else if (b < P_BTB0) {
        if (t < IN_DIM) buildBT_one(W_a, al_a, ar_a, BT_a, b - P_BTA0, t);
    } else {
        if (t < IN_DIM) buildBT_one(W_b, al_b, ar_b, BT_b, b - P_BTB0, t);
    }
}

// ---- megaF: gemm_a ∪ gemm_b ∪ merged fill (proven 128 µs; gemms fully
//      hidden under the fill's atomic/scatter floor) ----
__global__ __launch_bounds__(256) void megaF(
    const float* __restrict__ h,
    const unsigned short* __restrict__ BT_a, const unsigned short* __restrict__ BT_b,
    unsigned short* __restrict__ feat_a, unsigned short* __restrict__ feat_b,
    float* __restrict__ el_a, float* __restrict__ er_a,
    float* __restrict__ el_b, float* __restrict__ er_b,
    const int* __restrict__ src_a, const int* __restrict__ dst_a,
    const int* __restrict__ src_b, const int* __restrict__ dst_b,
    int* __restrict__ counts_a, int* __restrict__ counts_b,
    unsigned short* __restrict__ perm_a, unsigned short* __restrict__ perm_b)
{
    int b = blockIdx.x, t = threadIdx.x;
    if (b >= F_GEMM) {
        int idx = (b - F_GEMM) * 256 + t;
        if (idx < EE) dev_fill(idx, src_a, dst_a, counts_a, perm_a);
        else          dev_fill(idx - EE, src_b, dst_b, counts_b, perm_b);
        return;
    }
    int mp = (b >= GEMM_BLKS);
    int gb = mp ? b - GEMM_BLKS : b;
    dev_gemm(gb, t, h,
             mp ? BT_b : BT_a, mp ? feat_b : feat_a,
             mp ? el_b : el_a, mp ? er_b : er_a);
}

// ---- megaC-v3: merged pulls + fused PER-WAVE semantic q (megaD deleted).
//      Gather path unchanged (fabric/latency floor ~124 µs merged).
//      Sem fusion rules learned R4/R6: NO cross-wave barrier (waves stay
//      independent; LDS handoff is wave-internal, lgkmcnt-synced), NO big
//      LDS (2 KB/block), occupancy stays 8 waves/EU.
//      Sem math: A-frag rows all duplicate the node's z-row (C row i depends
//      only on A row i, so duplicate rows are self-consistent); every lane's
//      c[0] = s_{jt*16+(lane&15)}; 16-lane xor-reduce -> q_n; spread atomics. ----
__global__ __launch_bounds__(256, 8) void megaC(
    const int* __restrict__ counts_a, const int* __restrict__ counts_b,
    const unsigned short* __restrict__ perm_a, const unsigned short* __restrict__ perm_b,
    const float* __restrict__ el_a, const float* __restrict__ er_a,
    const float* __restrict__ el_b, const float* __restrict__ er_b,
    const unsigned short* __restrict__ feat_a, const unsigned short* __restrict__ feat_b,
    const float* __restrict__ bias_a, const float* __restrict__ bias_b,
    unsigned short* __restrict__ zb_a, unsigned short* __restrict__ zb_b,
    const unsigned short* __restrict__ WsemT,
    const float* __restrict__ bsem, const float* __restrict__ wsem,
    float* __restrict__ qsumP)
{
    __shared__ __align__(16) unsigned short zlds[4][256];
    int bb = blockIdx.x;
    int mp = (bb >= PULL_G);
    int blk = mp ? bb - PULL_G : bb;
    const int* counts = mp ? counts_b : counts_a;
    const unsigned short* perm = mp ? perm_b : perm_a;
    const float* el = mp ? el_b : el_a;
    const float* er = mp ? er_b : er_a;
    const unsigned short* feat = mp ? feat_b : feat_a;
    const float* bias = mp ? bias_b : bias_a;
    unsigned short* zb = mp ? zb_b : zb_a;

    int wave = threadIdx.x >> 6;
    int lane = threadIdx.x & 63;
    int n = blk * 4 + wave;           // PULL_G*4 == NN exactly
    int sub = lane >> 5;              // which edge-parity class for this half
    int l32 = lane & 31;
    int head = l32 >> 2;              // 4 lanes per head
    int fbase = l32 * 8;              // 8 contiguous features per lane
    int deg = counts[n * CSTRIDE];
    if (deg > CAP) deg = CAP;
    int base = n * CAP;
    float ern = er[n * HEADS + head];
    float den = 0.f;
    f32x2 acc2[4];
    #pragma unroll
    for (int u = 0; u < 4; ++u) { acc2[u][0] = 0.f; acc2[u][1] = 0.f; }

#define PROC(EV, FV) {                                               \
        float x = (EV) + ern;                                        \
        x = fmaxf(x, 0.2f * x);                                      \
        float ex = __expf(x);                                        \
        den += ex;                                                   \
        f32x2 ex2; ex2[0] = ex; ex2[1] = ex;                         \
        const unsigned int* fp = (const unsigned int*)&(FV);         \
        _Pragma("unroll")                                            \
        for (int u = 0; u < 4; ++u) {                                \
            union { unsigned int i; float f; } lo, hi;               \
            lo.i = fp[u] << 16; hi.i = fp[u] & 0xFFFF0000u;          \
            f32x2 v; v[0] = lo.f; v[1] = hi.f;                       \
            acc2[u] += v * ex2;                                      \
        } }

    int jp = sub;
    #pragma unroll 1
    for (; jp + 6 < deg; jp += 8) {      // 4 edges in flight for this half
        int s0 = perm[base + jp];
        int s1 = perm[base + jp + 2];
        int s2 = perm[base + jp + 4];
        int s3 = perm[base + jp + 6];
        float e0 = el[s0 * HEADS + head];
        float e1 = el[s1 * HEADS + head];
        float e2 = el[s2 * HEADS + head];
        float e3 = el[s3 * HEADS + head];
        uint4 f0 = *(const uint4*)(feat + (size_t)s0 * FF + fbase);
        uint4 f1 = *(const uint4*)(feat + (size_t)s1 * FF + fbase);
        uint4 f2 = *(const uint4*)(feat + (size_t)s2 * FF + fbase);
        uint4 f3 = *(const uint4*)(feat + (size_t)s3 * FF + fbase);
        PROC(e0, f0); PROC(e1, f1); PROC(e2, f2); PROC(e3, f3);
    }
    #pragma unroll 1
    for (; jp + 2 < deg; jp += 4) {      // 2 edges in flight
        int s0 = perm[base + jp];
        int s1 = perm[base + jp + 2];
        float e0 = el[s0 * HEADS + head];
        float e1 = el[s1 * HEADS + head];
        uint4 f0 = *(const uint4*)(feat + (size_t)s0 * FF + fbase);
        uint4 f1 = *(const uint4*)(feat + (size_t)s1 * FF + fbase);
        PROC(e0, f0); PROC(e1, f1);
    }
    if (jp < deg) {
        int s0 = perm[base + jp];
        float e0 = el[s0 * HEADS + head];
        uint4 f0 = *(const uint4*)(feat + (size_t)s0 * FF + fbase);
        PROC(e0, f0);
    }
#undef PROC

    float accf[8];
    #pragma unroll
    for (int u = 0; u < 4; ++u) {
        accf[2 * u]     = acc2[u][0];
        accf[2 * u + 1] = acc2[u][1];
    }

    // combine the two halves (lane^32 holds same features, other edge set)
    den += __shfl_xor(den, 32, 64);
    #pragma unroll
    for (int u = 0; u < 8; ++u) accf[u] += __shfl_xor(accf[u], 32, 64);

    if (den <= 0.f) den = 1.f;
    float inv = 1.f / den;
    float4 b0 = *(const float4*)(bias + fbase);
    float4 b1 = *(const float4*)(bias + fbase + 4);
    float bv[8] = {b0.x, b0.y, b0.z, b0.w, b1.x, b1.y, b1.z, b1.w};

    // both halves hold identical accf/den -> both compute rr (z row, bf16)
    unsigned short rr[8];
    #pragma unroll
    for (int u = 0; u < 8; ++u) {
        float ov = accf[u] * inv + bv[u];
        ov = (ov > 0.f) ? ov : (__expf(ov) - 1.f);
        rr[u] = f2b(ov);
    }
    if (sub == 0) {
        ushort4 r0, r1;
        r0.x = rr[0]; r0.y = rr[1]; r0.z = rr[2]; r0.w = rr[3];
        r1.x = rr[4]; r1.y = rr[5]; r1.z = rr[6]; r1.w = rr[7];
        *(ushort4*)(zb + (size_t)n * FF + fbase) = r0;
        *(ushort4*)(zb + (size_t)n * FF + fbase + 4) = r1;
        // stage z into this wave's private LDS slot (wave-internal handoff)
        s16x8 zv;
        #pragma unroll
        for (int u = 0; u < 8; ++u) zv[u] = (short)rr[u];
        *(s16x8*)&zlds[wave][fbase] = zv;
    }
    // wave-synchronous LDS visibility: no __syncthreads (waves independent)
    asm volatile("s_waitcnt lgkmcnt(0)" ::: "memory");
    __builtin_amdgcn_sched_barrier(0);

    // ---- fused per-wave semantic projection: q_n via 64 MFMA on idle pipe.
    //      A-frag: z chunk [kk*32 + quad*8, +8) -> all 16 A-rows identical.
    int quad = lane >> 4, col = lane & 15;
    s16x8 af[8];
    #pragma unroll
    for (int kk = 0; kk < 8; ++kk)
        af[kk] = *(const s16x8*)&zlds[wave][kk * 32 + quad * 8];
    float qpart = 0.f;
    #pragma unroll 1
    for (int jt = 0; jt < 8; ++jt) {
        int j = jt * 16 + col;
        const unsigned short* brow = WsemT + (size_t)j * FF + quad * 8;
        f32x4 c = {0.f, 0.f, 0.f, 0.f};
        #pragma unroll
        for (int kk = 0; kk < 8; ++kk) {
            s16x8 bf = *(const s16x8*)(brow + kk * 32);
            c = __builtin_amdgcn_mfma_f32_16x16x32_bf16(af[kk], bf, c, 0, 0, 0);
        }
        float y = c[0] + bsem[j];
        y = fminf(fmaxf(y, -10.f), 10.f);
        float t = __expf(2.f * y);
        qpart += (t - 1.f) * __builtin_amdgcn_rcpf(t + 1.f) * wsem[j];
    }
    // reduce the 16 cols (quads are duplicates; xor-reduce stays in-group)
    qpart += __shfl_xor(qpart, 1, 64);
    qpart += __shfl_xor(qpart, 2, 64);
    qpart += __shfl_xor(qpart, 4, 64);
    qpart += __shfl_xor(qpart, 8, 64);
    if (lane == 0)
        atomicAdd(&qsumP[(mp * QSLOTS + (blk & (QSLOTS - 1))) * 16], qpart);
}

// ---- combine: out = beta0*za + beta1*zbm. 16 B bf16 reads + 32 B fp32
//      writes per thread; qsum read from 32 spread slots (uniform scalar). ----
__global__ __launch_bounds__(256) void combine_kernel(
    const unsigned short* __restrict__ za,
    const unsigned short* __restrict__ zbm,
    float* __restrict__ out, const float* __restrict__ qsumP)
{
    size_t i = (size_t)blockIdx.x * blockDim.x + threadIdx.x;
    size_t base = i * 8;
    if (base >= (size_t)NN * FF) return;
    float qa = 0.f, qb = 0.f;
    #pragma unroll
    for (int s = 0; s < QSLOTS; ++s) {
        qa += qsumP[s * 16];
        qb += qsumP[(QSLOTS + s) * 16];
    }
    qa *= (1.f / NN); qb *= (1.f / NN);
    float mx = fmaxf(qa, qb);
    float ea = __expf(qa - mx), eb = __expf(qb - mx);
    float inv = 1.f / (ea + eb);
    float b0 = ea * inv, b1 = eb * inv;
    uint4 va = *(const uint4*)(za + base);
    uint4 vb = *(const uint4*)(zbm + base);
    const unsigned short* pa = (const unsigned short*)&va;
    const unsigned short* pb = (const unsigned short*)&vb;
    float4 r0, r1;
    r0.x = b0 * b2f(pa[0]) + b1 * b2f(pb[0]);
    r0.y = b0 * b2f(pa[1]) + b1 * b2f(pb[1]);
    r0.z = b0 * b2f(pa[2]) + b1 * b2f(pb[2]);
    r0.w = b0 * b2f(pa[3]) + b1 * b2f(pb[3]);
    r1.x = b0 * b2f(pa[4]) + b1 * b2f(pb[4]);
    r1.y = b0 * b2f(pa[5]) + b1 * b2f(pb[5]);
    r1.z = b0 * b2f(pa[6]) + b1 * b2f(pb[6]);
    r1.w = b0 * b2f(pa[7]) + b1 * b2f(pb[7]);
    *(float4*)(out + base) = r0;
    *(float4*)(out + base + 4) = r1;
}

extern "C" void kernel_launch(void* const* d_in, const int* in_sizes, int n_in,
                              void* d_out, int out_size, void* d_ws, size_t ws_size,
                              hipStream_t stream)
{
    const float* h      = (const float*)d_in[0];
    const int* src_a    = (const int*)d_in[1];
    const int* dst_a    = (const int*)d_in[2];
    const int* src_b    = (const int*)d_in[3];
    const int* dst_b    = (const int*)d_in[4];
    const float* W_a    = (const float*)d_in[5];
    const float* al_a   = (const float*)d_in[6];
    const float* ar_a   = (const float*)d_in[7];
    const float* bias_a = (const float*)d_in[8];
    const float* W_b    = (const float*)d_in[9];
    const float* al_b   = (const float*)d_in[10];
    const float* ar_b   = (const float*)d_in[11];
    const float* bias_b = (const float*)d_in[12];
    const float* Wsem   = (const float*)d_in[13];
    const float* bsem   = (const float*)d_in[14];
    const float* wsem   = (const float*)d_in[15];
    float* out = (float*)d_out;

    char* ws = (char*)d_ws;
    size_t o = 0;
    auto alloc = [&](size_t bytes) -> char* {
        char* p = ws + o;
        o += (bytes + 255) & ~(size_t)255;
        return p;
    };
    unsigned short* BT_a   = (unsigned short*)alloc((size_t)FEXT * IN_DIM * 2);
    unsigned short* BT_b   = (unsigned short*)alloc((size_t)FEXT * IN_DIM * 2);
    unsigned short* feat_a = (unsigned short*)alloc((size_t)NN * FF * 2);
    unsigned short* feat_b = (unsigned short*)alloc((size_t)NN * FF * 2);
    unsigned short* zb_a   = (unsigned short*)alloc((size_t)NPAD * FF * 2);
    unsigned short* zb_b   = (unsigned short*)alloc((size_t)NPAD * FF * 2);
    unsigned short* WsemT  = (unsigned short*)alloc((size_t)SH * FF * 2);
    float* el_a    = (float*)alloc((size_t)NN * HEADS * 4);
    float* er_a    = (float*)alloc((size_t)NN * HEADS * 4);
    float* el_b    = (float*)alloc((size_t)NN * HEADS * 4);
    float* er_b    = (float*)alloc((size_t)NN * HEADS * 4);
    unsigned short* perm_a = (unsigned short*)alloc((size_t)NN * CAP * 2);
    unsigned short* perm_b = (unsigned short*)alloc((size_t)NN * CAP * 2);
    // contiguous zero-init span: counts_a, counts_b (line-padded), qsumP
    char* zspan0   = ws + o;
    int* counts_a  = (int*)alloc((size_t)NN * CSTRIDE * 4);
    int* counts_b  = (int*)alloc((size_t)NN * CSTRIDE * 4);
    float* qsumP   = (float*)alloc((size_t)2 * QSLOTS * 16 * 4);
    size_t zspan   = (size_t)((ws + o) - zspan0);

    hipMemsetAsync(zspan0, 0, zspan, stream);
    prep<<<P_G, 256, 0, stream>>>(Wsem, WsemT,
                                  W_a, al_a, ar_a, BT_a,
                                  W_b, al_b, ar_b, BT_b);
    megaF<<<F_G, 256, 0, stream>>>(h, BT_a, BT_b, feat_a, feat_b,
                                   el_a, er_a, el_b, er_b,
                                   src_a, dst_a, src_b, dst_b,
                                   counts_a, counts_b, perm_a, perm_b);
    megaC<<<C_G, 256, 0, stream>>>(counts_a, counts_b, perm_a, perm_b,
                                   el_a, er_a, el_b, er_b,
                                   feat_a, feat_b, bias_a, bias_b, zb_a, zb_b,
                                   WsemT, bsem, wsem, qsumP);
    combine_kernel<<<(int)(((size_t)NN * FF / 8 + 255) / 256), 256, 0, stream>>>(zb_a, zb_b, out, qsumP);
}

// Round 10
// 424.486 us; speedup vs baseline: 2.3445x; 2.3445x over previous
//
#include <hip/hip_runtime.h>
#include <stdint.h>

#define NN 50000
#define EE 800000
#define IN_DIM 128
#define OUT_DIM 32
#define HEADS 8
#define FF 256
#define SH 128
#define NPAD 50048     // NN rounded up to 64
#define FEXT 272       // 256 feat cols + 8 el-proj + 8 er-proj
#define CAP 64         // per-dst bucket capacity (max degree ~45 << 64)
#define CSTRIDE 16     // one counter per 64B line (kills atomic line contention)

#define GEMM_BLKS 782  // NPAD/64
#define FILL_G   6250  // 2*EE/256 — merged fill (2x line parallelism = 128 µs floor)
#define PULL_G   12500 // NN/4

// prep blocks: WsemT (128) + BT_a (FEXT) + BT_b (FEXT)
#define P_BTA0   128
#define P_BTB0   (P_BTA0 + FEXT)
#define P_G      (P_BTB0 + FEXT)

// megaF: gemm blocks FIRST (seed CUs with MFMA work), merged fill floods after
#define F_GEMM   (2 * GEMM_BLKS)
#define F_G      (F_GEMM + FILL_G)

#define C_G      (2 * PULL_G)   // merged pulls (proven 123-125 µs)
#define D_G      (2 * GEMM_BLKS)

#define QSLOTS   16    // qsum spread: 16 line-padded accumulators per metapath

typedef short s16x8 __attribute__((ext_vector_type(8)));
typedef float f32x4 __attribute__((ext_vector_type(4)));
typedef float f32x2 __attribute__((ext_vector_type(2)));

__device__ __forceinline__ float b2f(unsigned short u) {
    union { unsigned int i; float f; } v; v.i = ((unsigned int)u) << 16; return v.f;
}
__device__ __forceinline__ unsigned short f2b(float f) {
    union { float f; unsigned int i; } v; v.f = f;
    unsigned int i = v.i;
    unsigned int r = (i + 0x7FFFu + ((i >> 16) & 1u)) >> 16;
    return (unsigned short)r;
}

__device__ __forceinline__ void buildBT_one(
    const float* __restrict__ W, const float* __restrict__ al,
    const float* __restrict__ ar, unsigned short* __restrict__ BT,
    int fp, int k)
{
    float v;
    if (fp < FF) {
        v = W[(size_t)k * FF + fp];
    } else if (fp < FF + 8) {
        int hh = fp - FF;
        float s = 0.f;
        #pragma unroll
        for (int d = 0; d < 32; ++d) s += W[(size_t)k * FF + hh * 32 + d] * al[hh * 32 + d];
        v = s;
    } else {
        int hh = fp - FF - 8;
        float s = 0.f;
        #pragma unroll
        for (int d = 0; d < 32; ++d) s += W[(size_t)k * FF + hh * 32 + d] * ar[hh * 32 + d];
        v = s;
    }
    BT[(size_t)fp * IN_DIM + k] = f2b(v);
}

// ---- fill: one edge per thread; rank from atomicAdd return ----
__device__ __forceinline__ void dev_fill(
    int idx, const int* __restrict__ src, const int* __restrict__ dst,
    int* __restrict__ counts, unsigned short* __restrict__ perm)
{
    int d = dst[idx];
    int r = atomicAdd(&counts[d * CSTRIDE], 1);
    if (r < CAP) perm[d * CAP + r] = (unsigned short)src[idx];
}

// ---- gemm: feat = h@W (bf16 MFMA), el/er fused as extra BT columns ----
__device__ __forceinline__ void dev_gemm(
    int gb, int t, const float* __restrict__ h,
    const unsigned short* __restrict__ BT,
    unsigned short* __restrict__ feat,
    float* __restrict__ el, float* __restrict__ er)
{
    int wave = t >> 6, lane = t & 63;
    int quad = lane >> 4, l16 = lane & 15;
    int nbase = gb * 64 + wave * 16;
    int n = nbase + l16;
    int nr = (n < NN) ? n : (NN - 1);   // clamp: pad rows must not read OOB
    const float* hrow = h + (size_t)nr * IN_DIM + quad * 8;
    s16x8 nfr[4];
    #pragma unroll
    for (int kt = 0; kt < 4; ++kt) {
        float4 p0 = *(const float4*)(hrow + kt * 32);
        float4 p1 = *(const float4*)(hrow + kt * 32 + 4);
        s16x8 v;
        v[0] = (short)f2b(p0.x); v[1] = (short)f2b(p0.y);
        v[2] = (short)f2b(p0.z); v[3] = (short)f2b(p0.w);
        v[4] = (short)f2b(p1.x); v[5] = (short)f2b(p1.y);
        v[6] = (short)f2b(p1.z); v[7] = (short)f2b(p1.w);
        nfr[kt] = v;
    }
    bool live = (n < NN);
    #pragma unroll 1
    for (int ft = 0; ft < 17; ++ft) {
        const unsigned short* brow = BT + (size_t)(ft * 16 + l16) * IN_DIM + quad * 8;
        f32x4 c = {0.f, 0.f, 0.f, 0.f};
        #pragma unroll
        for (int kt = 0; kt < 4; ++kt) {
            s16x8 ffr = *(const s16x8*)(brow + kt * 32);
            c = __builtin_amdgcn_mfma_f32_16x16x32_bf16(ffr, nfr[kt], c, 0, 0, 0);
        }
        if (ft < 16) {
            if (live) {
                ushort4 r;
                r.x = f2b(c[0]); r.y = f2b(c[1]); r.z = f2b(c[2]); r.w = f2b(c[3]);
                *(ushort4*)(feat + (size_t)n * FF + ft * 16 + quad * 4) = r;
            }
        } else if (live) {
            #pragma unroll
            for (int r = 0; r < 4; ++r) {
                int jp = quad * 4 + r;
                if (jp < 8) el[n * HEADS + jp] = c[r];
                else        er[n * HEADS + (jp - 8)] = c[r];
            }
        }
    }
}

// ---- pull: 1 node/wave, 2 halves × 4 edges in flight, 16 B feat loads,
//      packed bf16→f32 unpack + f32x2 FMA, cross-half shfl reduction.
//      Fabric/latency floor: FETCH 424 MB ≈ 8 XCDs × 51 MB working set.
//      R4/R7 laws: no cross-wave coupling, no per-wave sem work here. ----
__device__ __forceinline__ void dev_pull(
    int blk, int tid,
    const int* __restrict__ counts, const unsigned short* __restrict__ perm,
    const float* __restrict__ el, const float* __restrict__ er,
    const unsigned short* __restrict__ feat, const float* __restrict__ bias,
    unsigned short* __restrict__ zb)
{
    int wave = tid >> 6;
    int lane = tid & 63;
    int n = blk * 4 + wave;           // PULL_G*4 == NN exactly
    int sub = lane >> 5;              // which edge-parity class for this half
    int l32 = lane & 31;
    int head = l32 >> 2;              // 4 lanes per head
    int fbase = l32 * 8;              // 8 contiguous features per lane
    int deg = counts[n * CSTRIDE];
    if (deg > CAP) deg = CAP;
    int base = n * CAP;
    float ern = er[n * HEADS + head];
    float den = 0.f;
    f32x2 acc2[4];
    #pragma unroll
    for (int u = 0; u < 4; ++u) { acc2[u][0] = 0.f; acc2[u][1] = 0.f; }

#define PROC(EV, FV) {                                               \
        float x = (EV) + ern;                                        \
        x = fmaxf(x, 0.2f * x);                                      \
        float ex = __expf(x);                                        \
        den += ex;                                                   \
        f32x2 ex2; ex2[0] = ex; ex2[1] = ex;                         \
        const unsigned int* fp = (const unsigned int*)&(FV);         \
        _Pragma("unroll")                                            \
        for (int u = 0; u < 4; ++u) {                                \
            union { unsigned int i; float f; } lo, hi;               \
            lo.i = fp[u] << 16; hi.i = fp[u] & 0xFFFF0000u;          \
            f32x2 v; v[0] = lo.f; v[1] = hi.f;                       \
            acc2[u] += v * ex2;                                      \
        } }

    int jp = sub;
    #pragma unroll 1
    for (; jp + 6 < deg; jp += 8) {      // 4 edges in flight for this half
        int s0 = perm[base + jp];
        int s1 = perm[base + jp + 2];
        int s2 = perm[base + jp + 4];
        int s3 = perm[base + jp + 6];
        float e0 = el[s0 * HEADS + head];
        float e1 = el[s1 * HEADS + head];
        float e2 = el[s2 * HEADS + head];
        float e3 = el[s3 * HEADS + head];
        uint4 f0 = *(const uint4*)(feat + (size_t)s0 * FF + fbase);
        uint4 f1 = *(const uint4*)(feat + (size_t)s1 * FF + fbase);
        uint4 f2 = *(const uint4*)(feat + (size_t)s2 * FF + fbase);
        uint4 f3 = *(const uint4*)(feat + (size_t)s3 * FF + fbase);
        PROC(e0, f0); PROC(e1, f1); PROC(e2, f2); PROC(e3, f3);
    }
    #pragma unroll 1
    for (; jp + 2 < deg; jp += 4) {      // 2 edges in flight
        int s0 = perm[base + jp];
        int s1 = perm[base + jp + 2];
        float e0 = el[s0 * HEADS + head];
        float e1 = el[s1 * HEADS + head];
        uint4 f0 = *(const uint4*)(feat + (size_t)s0 * FF + fbase);
        uint4 f1 = *(const uint4*)(feat + (size_t)s1 * FF + fbase);
        PROC(e0, f0); PROC(e1, f1);
    }
    if (jp < deg) {
        int s0 = perm[base + jp];
        float e0 = el[s0 * HEADS + head];
        uint4 f0 = *(const uint4*)(feat + (size_t)s0 * FF + fbase);
        PROC(e0, f0);
    }
#undef PROC

    float accf[8];
    #pragma unroll
    for (int u = 0; u < 4; ++u) {
        accf[2 * u]     = acc2[u][0];
        accf[2 * u + 1] = acc2[u][1];
    }

    // combine the two halves (lane^32 holds same features, other edge set)
    den += __shfl_xor(den, 32, 64);
    #pragma unroll
    for (int u = 0; u < 8; ++u) accf[u] += __shfl_xor(accf[u], 32, 64);

    if (den <= 0.f) den = 1.f;
    float inv = 1.f / den;
    float4 b0 = *(const float4*)(bias + fbase);
    float4 b1 = *(const float4*)(bias + fbase + 4);
    float bv[8] = {b0.x, b0.y, b0.z, b0.w, b1.x, b1.y, b1.z, b1.w};
    if (sub == 0) {
        ushort4 r0, r1;
        unsigned short rr[8];
        #pragma unroll
        for (int u = 0; u < 8; ++u) {
            float ov = accf[u] * inv + bv[u];
            ov = (ov > 0.f) ? ov : (__expf(ov) - 1.f);
            rr[u] = f2b(ov);
        }
        r0.x = rr[0]; r0.y = rr[1]; r0.z = rr[2]; r0.w = rr[3];
        r1.x = rr[4]; r1.y = rr[5]; r1.z = rr[6]; r1.w = rr[7];
        *(ushort4*)(zb + (size_t)n * FF + fbase) = r0;
        *(ushort4*)(zb + (size_t)n * FF + fbase + 4) = r1;
    }
}

// ---- prep: WsemT ∪ BT_a ∪ BT_b (tiny) ----
__global__ __launch_bounds__(256) void prep(
    const float* __restrict__ Wsem, unsigned short* __restrict__ WsemT,
    const float* __restrict__ W_a, const float* __restrict__ al_a,
    const float* __restrict__ ar_a, unsigned short* __restrict__ BT_a,
    const float* __restrict__ W_b, const float* __restrict__ al_b,
    const float* __restrict__ ar_b, unsigned short* __restrict__ BT_b)
{
    int b = blockIdx.x, t = threadIdx.x;
    if (b < P_BTA0) {
        WsemT[b * FF + t] = f2b(Wsem[(size_t)t * SH + b]);
    } else if (b < P_BTB0) {
        if (t < IN_DIM) buildBT_one(W_a, al_a, ar_a, BT_a, b - P_BTA0, t);
    } else {
        if (t < IN_DIM) buildBT_one(W_b, al_b, ar_b, BT_b, b - P_BTB0, t);
    }
}

// ---- megaF: gemm_a ∪ gemm_b ∪ merged fill (proven 128 µs; gemms fully
//      hidden under the fill's atomic/scatter floor) ----
__global__ __launch_bounds__(256) void megaF(
    const float* __restrict__ h,
    const unsigned short* __restrict__ BT_a, const unsigned short* __restrict__ BT_b,
    unsigned short* __restrict__ feat_a, unsigned short* __restrict__ feat_b,
    float* __restrict__ el_a, float* __restrict__ er_a,
    float* __restrict__ el_b, float* __restrict__ er_b,
    const int* __restrict__ src_a, const int* __restrict__ dst_a,
    const int* __restrict__ src_b, const int* __restrict__ dst_b,
    int* __restrict__ counts_a, int* __restrict__ counts_b,
    unsigned short* __restrict__ perm_a, unsigned short* __restrict__ perm_b)
{
    int b = blockIdx.x, t = threadIdx.x;
    if (b >= F_GEMM) {
        int idx = (b - F_GEMM) * 256 + t;
        if (idx < EE) dev_fill(idx, src_a, dst_a, counts_a, perm_a);
        else          dev_fill(idx - EE, src_b, dst_b, counts_b, perm_b);
        return;
    }
    int mp = (b >= GEMM_BLKS);
    int gb = mp ? b - GEMM_BLKS : b;
    dev_gemm(gb, t, h,
             mp ? BT_b : BT_a, mp ? feat_b : feat_a,
             mp ? el_b : el_a, mp ? er_b : er_a);
}

// ---- megaC: pull_a ∪ pull_b merged, CLEAN (R1-proven 123-125 µs) ----
__global__ __launch_bounds__(256, 8) void megaC(
    const int* __restrict__ counts_a, const int* __restrict__ counts_b,
    const unsigned short* __restrict__ perm_a, const unsigned short* __restrict__ perm_b,
    const float* __restrict__ el_a, const float* __restrict__ er_a,
    const float* __restrict__ el_b, const float* __restrict__ er_b,
    const unsigned short* __restrict__ feat_a, const unsigned short* __restrict__ feat_b,
    const float* __restrict__ bias_a, const float* __restrict__ bias_b,
    unsigned short* __restrict__ zb_a, unsigned short* __restrict__ zb_b)
{
    int bb = blockIdx.x;
    int mp = (bb >= PULL_G);
    int blk = mp ? bb - PULL_G : bb;
    dev_pull(blk, threadIdx.x,
             mp ? counts_b : counts_a, mp ? perm_b : perm_a,
             mp ? el_b : el_a, mp ? er_b : er_a,
             mp ? feat_b : feat_a, mp ? bias_b : bias_a,
             mp ? zb_b : zb_a);
}

// ---- megaD-v3: sem_a ∪ sem_b. Anti-spill rewrite of the R1-R3 semD:
//      `#pragma unroll 1` on the jt loop keeps only 8 B-fragments live
//      (R3's full unroll hoisted 64 -> ~256 VGPR -> scratch spills, the
//      suspected 15x-over-arithmetic cost). No LDS, no __syncthreads:
//      per-wave shfl reduce + spread-slot atomic. 64 nodes/block batches
//      WsemT reads (1 KB/node — the R7 law). exp-based tanh. ----
__global__ __launch_bounds__(256) void megaD(
    const unsigned short* __restrict__ zb_a, const unsigned short* __restrict__ zb_b,
    const unsigned short* __restrict__ WsemT,
    const float* __restrict__ bsem, const float* __restrict__ wsem,
    float* __restrict__ qsumP)
{
    int bb = blockIdx.x;
    int mp = (bb >= GEMM_BLKS);
    int blk = mp ? bb - GEMM_BLKS : bb;
    const unsigned short* zb = mp ? zb_b : zb_a;

    int wave = threadIdx.x >> 6, lane = threadIdx.x & 63;
    int quad = lane >> 4, l16 = lane & 15;
    int nbase = blk * 64 + wave * 16;
    const unsigned short* arow = zb + (size_t)(nbase + l16) * FF + quad * 8;
    s16x8 afr[8];
    #pragma unroll
    for (int kt = 0; kt < 8; ++kt)
        afr[kt] = *(const s16x8*)(arow + kt * 32);
    float qacc = 0.f;
    #pragma unroll 1
    for (int jt = 0; jt < 8; ++jt) {
        int jj = jt * 16 + l16;
        const unsigned short* brow = WsemT + (size_t)jj * FF + quad * 8;
        f32x4 c = {0.f, 0.f, 0.f, 0.f};
        #pragma unroll
        for (int kt = 0; kt < 8; ++kt) {
            s16x8 bfr = *(const s16x8*)(brow + kt * 32);
            c = __builtin_amdgcn_mfma_f32_16x16x32_bf16(afr[kt], bfr, c, 0, 0, 0);
        }
        float bj = bsem[jj], wj = wsem[jj];
        #pragma unroll
        for (int r = 0; r < 4; ++r) {
            int n = nbase + quad * 4 + r;
            float y = c[r] + bj;
            y = fminf(fmaxf(y, -10.f), 10.f);
            float t = __expf(2.f * y);
            float tv = (t - 1.f) * __builtin_amdgcn_rcpf(t + 1.f) * wj;
            qacc += (n < NN) ? tv : 0.f;
        }
    }
    #pragma unroll
    for (int o = 1; o < 64; o <<= 1) qacc += __shfl_xor(qacc, o, 64);
    if (lane == 0)
        atomicAdd(&qsumP[(mp * QSLOTS + (blk & (QSLOTS - 1))) * 16], qacc);
}

// ---- combine: out = beta0*za + beta1*zbm. 16 B bf16 reads + 32 B fp32
//      writes per thread; qsum from 32 spread slots (uniform scalar). ----
__global__ __launch_bounds__(256) void combine_kernel(
    const unsigned short* __restrict__ za,
    const unsigned short* __restrict__ zbm,
    float* __restrict__ out, const float* __restrict__ qsumP)
{
    size_t i = (size_t)blockIdx.x * blockDim.x + threadIdx.x;
    size_t base = i * 8;
    if (base >= (size_t)NN * FF) return;
    float qa = 0.f, qb = 0.f;
    #pragma unroll
    for (int s = 0; s < QSLOTS; ++s) {
        qa += qsumP[s * 16];
        qb += qsumP[(QSLOTS + s) * 16];
    }
    qa *= (1.f / NN); qb *= (1.f / NN);
    float mx = fmaxf(qa, qb);
    float ea = __expf(qa - mx), eb = __expf(qb - mx);
    float inv = 1.f / (ea + eb);
    float b0 = ea * inv, b1 = eb * inv;
    uint4 va = *(const uint4*)(za + base);
    uint4 vb = *(const uint4*)(zbm + base);
    const unsigned short* pa = (const unsigned short*)&va;
    const unsigned short* pb = (const unsigned short*)&vb;
    float4 r0, r1;
    r0.x = b0 * b2f(pa[0]) + b1 * b2f(pb[0]);
    r0.y = b0 * b2f(pa[1]) + b1 * b2f(pb[1]);
    r0.z = b0 * b2f(pa[2]) + b1 * b2f(pb[2]);
    r0.w = b0 * b2f(pa[3]) + b1 * b2f(pb[3]);
    r1.x = b0 * b2f(pa[4]) + b1 * b2f(pb[4]);
    r1.y = b0 * b2f(pa[5]) + b1 * b2f(pb[5]);
    r1.z = b0 * b2f(pa[6]) + b1 * b2f(pb[6]);
    r1.w = b0 * b2f(pa[7]) + b1 * b2f(pb[7]);
    *(float4*)(out + base) = r0;
    *(float4*)(out + base + 4) = r1;
}

extern "C" void kernel_launch(void* const* d_in, const int* in_sizes, int n_in,
                              void* d_out, int out_size, void* d_ws, size_t ws_size,
                              hipStream_t stream)
{
    const float* h      = (const float*)d_in[0];
    const int* src_a    = (const int*)d_in[1];
    const int* dst_a    = (const int*)d_in[2];
    const int* src_b    = (const int*)d_in[3];
    const int* dst_b    = (const int*)d_in[4];
    const float* W_a    = (const float*)d_in[5];
    const float* al_a   = (const float*)d_in[6];
    const float* ar_a   = (const float*)d_in[7];
    const float* bias_a = (const float*)d_in[8];
    const float* W_b    = (const float*)d_in[9];
    const float* al_b   = (const float*)d_in[10];
    const float* ar_b   = (const float*)d_in[11];
    const float* bias_b = (const float*)d_in[12];
    const float* Wsem   = (const float*)d_in[13];
    const float* bsem   = (const float*)d_in[14];
    const float* wsem   = (const float*)d_in[15];
    float* out = (float*)d_out;

    char* ws = (char*)d_ws;
    size_t o = 0;
    auto alloc = [&](size_t bytes) -> char* {
        char* p = ws + o;
        o += (bytes + 255) & ~(size_t)255;
        return p;
    };
    unsigned short* BT_a   = (unsigned short*)alloc((size_t)FEXT * IN_DIM * 2);
    unsigned short* BT_b   = (unsigned short*)alloc((size_t)FEXT * IN_DIM * 2);
    unsigned short* feat_a = (unsigned short*)alloc((size_t)NN * FF * 2);
    unsigned short* feat_b = (unsigned short*)alloc((size_t)NN * FF * 2);
    unsigned short* zb_a   = (unsigned short*)alloc((size_t)NPAD * FF * 2);
    unsigned short* zb_b   = (unsigned short*)alloc((size_t)NPAD * FF * 2);
    unsigned short* WsemT  = (unsigned short*)alloc((size_t)SH * FF * 2);
    float* el_a    = (float*)alloc((size_t)NN * HEADS * 4);
    float* er_a    = (float*)alloc((size_t)NN * HEADS * 4);
    float* el_b    = (float*)alloc((size_t)NN * HEADS * 4);
    float* er_b    = (float*)alloc((size_t)NN * HEADS * 4);
    unsigned short* perm_a = (unsigned short*)alloc((size_t)NN * CAP * 2);
    unsigned short* perm_b = (unsigned short*)alloc((size_t)NN * CAP * 2);
    // contiguous zero-init span: counts_a, counts_b (line-padded), qsumP
    char* zspan0   = ws + o;
    int* counts_a  = (int*)alloc((size_t)NN * CSTRIDE * 4);
    int* counts_b  = (int*)alloc((size_t)NN * CSTRIDE * 4);
    float* qsumP   = (float*)alloc((size_t)2 * QSLOTS * 16 * 4);
    size_t zspan   = (size_t)((ws + o) - zspan0);

    hipMemsetAsync(zspan0, 0, zspan, stream);
    prep<<<P_G, 256, 0, stream>>>(Wsem, WsemT,
                                  W_a, al_a, ar_a, BT_a,
                                  W_b, al_b, ar_b, BT_b);
    megaF<<<F_G, 256, 0, stream>>>(h, BT_a, BT_b, feat_a, feat_b,
                                   el_a, er_a, el_b, er_b,
                                   src_a, dst_a, src_b, dst_b,
                                   counts_a, counts_b, perm_a, perm_b);
    megaC<<<C_G, 256, 0, stream>>>(counts_a, counts_b, perm_a, perm_b,
                                   el_a, er_a, el_b, er_b,
                                   feat_a, feat_b, bias_a, bias_b, zb_a, zb_b);
    megaD<<<D_G, 256, 0, stream>>>(zb_a, zb_b, WsemT, bsem, wsem, qsumP);
    combine_kernel<<<(int)(((size_t)NN * FF / 8 + 255) / 256), 256, 0, stream>>>(zb_a, zb_b, out, qsumP);
}